// Round 4
// baseline (625.291 us; speedup 1.0000x reference)
//
#include <hip/hip_runtime.h>
#include <hip/hip_bf16.h>
#include <math.h>

typedef __bf16 bf16_t;
typedef __bf16 bf16x8 __attribute__((ext_vector_type(8)));
typedef float f32x4 __attribute__((ext_vector_type(4)));

#define MFMA16(a,b,c) __builtin_amdgcn_mfma_f32_16x16x32_bf16((a),(b),(c),0,0,0)

// ---------------- fp32 [R][C] -> bf16 [C][R] transpose-convert ----------------
__global__ void k_transpose_cvt(const float* __restrict__ in, bf16_t* __restrict__ out,
                                int R, int C) {
  __shared__ float tile[32][33];
  int c0 = blockIdx.x * 32, r0 = blockIdx.y * 32;
  int x = threadIdx.x, y = threadIdx.y;  // block (32,8)
#pragma unroll
  for (int i = 0; i < 32; i += 8) tile[y + i][x] = in[(size_t)(r0 + y + i) * C + c0 + x];
  __syncthreads();
#pragma unroll
  for (int i = 0; i < 32; i += 8)
    out[(size_t)(c0 + y + i) * R + r0 + x] = (bf16_t)tile[x][y + i];
}

// ---------------- RoPE cos/sin table: [2048][16] each ----------------
__global__ void k_sincos(float* __restrict__ ct, float* __restrict__ st) {
  int idx = blockIdx.x * blockDim.x + threadIdx.x;  // 0..32767
  int pos = idx >> 4, i = idx & 15;
  float invf = powf(10000.0f, -(float)i / 16.0f);
  float ang = (float)pos * invf;
  ct[idx] = cosf(ang);
  st[idx] = sinf(ang);
}

// ---------------- bf16 MFMA GEMM: C[M][N] = A[M][K] @ Bt[N][K]^T + bias ----------------
// 128x128 tile, BK=64, 256 threads (4 waves 2x2), each wave 64x64 = 4x4 16x16 frags.
// A_FP32: A is fp32 (converted to bf16 during staging).
// EPI=0: plain store to C0 (fp32 if OUT_F32 else bf16).
// EPI=1: RoPE + head-split epilogue writing q/k/v [B*H][S][64] (C0=q, C1=k, C2=v), bf16.
template <int N, int K, bool A_FP32, int EPI, bool OUT_F32>
__global__ __launch_bounds__(256) void k_gemm(const void* __restrict__ Av,
                                              const bf16_t* __restrict__ Bt,
                                              const float* __restrict__ bias,
                                              void* __restrict__ C0, bf16_t* __restrict__ C1,
                                              bf16_t* __restrict__ C2,
                                              const float* __restrict__ ct,
                                              const float* __restrict__ st) {
  __shared__ alignas(16) bf16_t As[128 * 64];
  __shared__ alignas(16) bf16_t Bs[128 * 64];
  const int tid = threadIdx.x;
  const int lane = tid & 63;
  const int lane15 = lane & 15, g = lane >> 4;
  const int wave = tid >> 6;
  const int wr = wave >> 1, wc = wave & 1;
  const int rowBase = blockIdx.y * 128, colBase = blockIdx.x * 128;
  f32x4 acc[4][4] = {};
  for (int kt = 0; kt < K; kt += 64) {
    // stage A and Bt tiles: [128][64] bf16, 1024 16B-chunks each, 4 per thread
#pragma unroll
    for (int i = 0; i < 4; ++i) {
      int c = i * 256 + tid;
      int r = c >> 3, k8 = (c & 7) * 8;
      if constexpr (A_FP32) {
        const float* src = (const float*)Av + (size_t)(rowBase + r) * K + kt + k8;
        float4 a0 = *(const float4*)src;
        float4 a1 = *(const float4*)(src + 4);
        bf16x8 o;
        o[0] = (bf16_t)a0.x; o[1] = (bf16_t)a0.y; o[2] = (bf16_t)a0.z; o[3] = (bf16_t)a0.w;
        o[4] = (bf16_t)a1.x; o[5] = (bf16_t)a1.y; o[6] = (bf16_t)a1.z; o[7] = (bf16_t)a1.w;
        *(bf16x8*)&As[r * 64 + k8] = o;
      } else {
        *(bf16x8*)&As[r * 64 + k8] =
            *(const bf16x8*)((const bf16_t*)Av + (size_t)(rowBase + r) * K + kt + k8);
      }
      *(bf16x8*)&Bs[r * 64 + k8] = *(const bf16x8*)&Bt[(size_t)(colBase + r) * K + kt + k8];
    }
    __syncthreads();
#pragma unroll
    for (int kk = 0; kk < 2; ++kk) {
      bf16x8 af[4], bfr[4];
#pragma unroll
      for (int m = 0; m < 4; ++m)
        af[m] = *(const bf16x8*)&As[(wr * 64 + m * 16 + lane15) * 64 + kk * 32 + g * 8];
#pragma unroll
      for (int n = 0; n < 4; ++n)
        bfr[n] = *(const bf16x8*)&Bs[(wc * 64 + n * 16 + lane15) * 64 + kk * 32 + g * 8];
#pragma unroll
      for (int m = 0; m < 4; ++m)
#pragma unroll
        for (int n = 0; n < 4; ++n) acc[m][n] = MFMA16(af[m], bfr[n], acc[m][n]);
    }
    __syncthreads();
  }
  // C/D layout: col=lane&15, row=(lane>>4)*4+j  [guide m89/m91 verified]
  if constexpr (EPI == 0) {
#pragma unroll
    for (int m = 0; m < 4; ++m)
#pragma unroll
      for (int n = 0; n < 4; ++n) {
        int ccol = colBase + wc * 64 + n * 16 + lane15;
        float bb = bias[ccol];
#pragma unroll
        for (int j = 0; j < 4; ++j) {
          int crow = rowBase + wr * 64 + m * 16 + g * 4 + j;
          if constexpr (OUT_F32)
            ((float*)C0)[(size_t)crow * N + ccol] = acc[m][n][j] + bb;
          else
            ((bf16_t*)C0)[(size_t)crow * N + ccol] = (bf16_t)(acc[m][n][j] + bb);
        }
      }
  } else {
    // wave's 64-col block = exactly one head of one of {q,k,v}
    const int colb = colBase + wc * 64;  // 64-aligned
    const int which = colb >> 11;        // 0=q 1=k 2=v (uniform per wave)
    const int h = (colb >> 6) & 31;
    bf16_t* dst = which == 0 ? (bf16_t*)C0 : which == 1 ? C1 : C2;
    float bb[4];
#pragma unroll
    for (int n = 0; n < 4; ++n) bb[n] = bias[colb + n * 16 + lane15];
#pragma unroll
    for (int m = 0; m < 4; ++m)
#pragma unroll
      for (int j = 0; j < 4; ++j) {
        int row = rowBase + wr * 64 + m * 16 + g * 4 + j;
        int s = row & 2047, b = row >> 11;
        float v[4];
#pragma unroll
        for (int n = 0; n < 4; ++n) v[n] = acc[m][n][j] + bb[n];
        if (which < 2) {  // rope on dims [0..31]: pair (d, d+16), d = lane15
          float c = ct[s * 16 + lane15], sn = st[s * 16 + lane15];
          float a = v[0], b2 = v[1];
          v[0] = a * c - b2 * sn;
          v[1] = a * sn + b2 * c;
        }
        bf16_t* drow = dst + ((size_t)(b * 32 + h) * 2048 + s) * 64;
#pragma unroll
        for (int n = 0; n < 4; ++n) drow[n * 16 + lane15] = (bf16_t)v[n];
      }
  }
}

// ---------------- causal flash attention, MFMA 16x16x32 ----------------
// grid (S/64, B*H); 256 threads = 4 waves, wave w owns 16 queries.
__global__ __launch_bounds__(256) void k_attn(const bf16_t* __restrict__ q,
                                              const bf16_t* __restrict__ kbuf,
                                              const bf16_t* __restrict__ vbuf,
                                              bf16_t* __restrict__ attn_out) {
  __shared__ alignas(16) bf16_t Ks[64 * 64];
  __shared__ alignas(16) bf16_t Vt[64 * 64];     // transposed: Vt[d][kv]
  __shared__ alignas(16) bf16_t Ps[4 * 16 * 64]; // per-wave P tile
  const int qb = blockIdx.x;
  const int bh = blockIdx.y;
  const int b = bh >> 5, h = bh & 31;
  const int tid = threadIdx.x, lane = tid & 63, wave = tid >> 6;
  const size_t base = (size_t)bh * 2048 * 64;
  const int qg0 = qb * 64 + wave * 16;
  bf16x8 aq[2];
#pragma unroll
  for (int kk = 0; kk < 2; ++kk)
    aq[kk] = *(const bf16x8*)&q[base + (size_t)(qg0 + (lane & 15)) * 64 + kk * 32 + (lane >> 4) * 8];
  float m_r[4], l_r[4];
  f32x4 o[4] = {};
#pragma unroll
  for (int j = 0; j < 4; ++j) { m_r[j] = -INFINITY; l_r[j] = 0.f; }
  bf16_t* Pw = Ps + wave * 16 * 64;
  for (int t = 0; t <= qb; ++t) {
    {  // stage K tile [kv][d] and V^T tile [d][kv]
      int r = tid >> 2, d0 = (tid & 3) * 16;
      *(bf16x8*)&Ks[r * 64 + d0] = *(const bf16x8*)&kbuf[base + (size_t)(t * 64 + r) * 64 + d0];
      *(bf16x8*)&Ks[r * 64 + d0 + 8] = *(const bf16x8*)&kbuf[base + (size_t)(t * 64 + r) * 64 + d0 + 8];
      bf16x8 v0 = *(const bf16x8*)&vbuf[base + (size_t)(t * 64 + r) * 64 + d0];
      bf16x8 v1 = *(const bf16x8*)&vbuf[base + (size_t)(t * 64 + r) * 64 + d0 + 8];
#pragma unroll
      for (int j = 0; j < 8; ++j) {
        Vt[(d0 + j) * 64 + r] = v0[j];
        Vt[(d0 + 8 + j) * 64 + r] = v1[j];
      }
    }
    __syncthreads();
    // S = Q K^T  (C: col=key=lane&15, row=query=(lane>>4)*4+j)
    f32x4 sv[4];
#pragma unroll
    for (int n = 0; n < 4; ++n) {
      f32x4 acc = {};
#pragma unroll
      for (int kk = 0; kk < 2; ++kk) {
        bf16x8 bk = *(const bf16x8*)&Ks[(n * 16 + (lane & 15)) * 64 + kk * 32 + (lane >> 4) * 8];
        acc = MFMA16(aq[kk], bk, acc);
      }
      sv[n] = acc;
    }
    // scale + causal mask + online softmax
    float vmax[4];
#pragma unroll
    for (int j = 0; j < 4; ++j) vmax[j] = -INFINITY;
#pragma unroll
    for (int n = 0; n < 4; ++n) {
      int kvg = t * 64 + n * 16 + (lane & 15);
#pragma unroll
      for (int j = 0; j < 4; ++j) {
        int qg = qg0 + (lane >> 4) * 4 + j;
        float x = sv[n][j] * 0.125f;
        if (kvg > qg) x = -1e30f;
        sv[n][j] = x;
        vmax[j] = fmaxf(vmax[j], x);
      }
    }
#pragma unroll
    for (int off = 1; off < 16; off <<= 1)
#pragma unroll
      for (int j = 0; j < 4; ++j) vmax[j] = fmaxf(vmax[j], __shfl_xor(vmax[j], off));
    float corr[4], rs[4];
#pragma unroll
    for (int j = 0; j < 4; ++j) {
      float mn = fmaxf(m_r[j], vmax[j]);
      corr[j] = expf(m_r[j] - mn);  // first tile: exp(-inf)=0
      m_r[j] = mn;
      rs[j] = 0.f;
    }
#pragma unroll
    for (int n = 0; n < 4; ++n)
#pragma unroll
      for (int j = 0; j < 4; ++j) {
        float p = expf(sv[n][j] - m_r[j]);
        sv[n][j] = p;
        rs[j] += p;
      }
#pragma unroll
    for (int off = 1; off < 16; off <<= 1)
#pragma unroll
      for (int j = 0; j < 4; ++j) rs[j] += __shfl_xor(rs[j], off);
#pragma unroll
    for (int j = 0; j < 4; ++j) l_r[j] = l_r[j] * corr[j] + rs[j];
    // P -> LDS (bf16), becomes PV A-operand
#pragma unroll
    for (int n = 0; n < 4; ++n)
#pragma unroll
      for (int j = 0; j < 4; ++j)
        Pw[((lane >> 4) * 4 + j) * 64 + n * 16 + (lane & 15)] = (bf16_t)sv[n][j];
    __syncthreads();
    // O = O*corr + P @ V
#pragma unroll
    for (int f = 0; f < 4; ++f) {
      f32x4 on = o[f];
#pragma unroll
      for (int j = 0; j < 4; ++j) on[j] *= corr[j];
#pragma unroll
      for (int kk = 0; kk < 2; ++kk) {
        bf16x8 ap = *(const bf16x8*)&Pw[(lane & 15) * 64 + kk * 32 + (lane >> 4) * 8];
        bf16x8 bv = *(const bf16x8*)&Vt[(f * 16 + (lane & 15)) * 64 + kk * 32 + (lane >> 4) * 8];
        on = MFMA16(ap, bv, on);
      }
      o[f] = on;
    }
    __syncthreads();
  }
  // write attn_out[b*2048+qg][h*64 + f*16 + (lane&15)]
#pragma unroll
  for (int f = 0; f < 4; ++f)
#pragma unroll
    for (int j = 0; j < 4; ++j) {
      int qg = qg0 + (lane >> 4) * 4 + j;
      float val = o[f][j] / l_r[j];
      attn_out[(size_t)(b * 2048 + qg) * 2048 + h * 64 + f * 16 + (lane & 15)] = (bf16_t)val;
    }
}

extern "C" void kernel_launch(void* const* d_in, const int* in_sizes, int n_in, void* d_out,
                              int out_size, void* d_ws, size_t ws_size, hipStream_t stream) {
  const float* x = (const float*)d_in[0];
  const float* Wqkv = (const float*)d_in[1];
  const float* bqkv = (const float*)d_in[2];
  const float* Wo = (const float*)d_in[3];
  const float* bo = (const float*)d_in[4];
  // Reference output dtype is FLOAT32 (fp32 inputs -> fp32 JAX graph).
  float* out = (float*)d_out;

  char* ws = (char*)d_ws;
  size_t off = 0;
  auto carve = [&](size_t bytes) {
    void* p = ws + off;
    off += (bytes + 255) & ~(size_t)255;
    return p;
  };
  bf16_t* wqkv_t = (bf16_t*)carve((size_t)6144 * 2048 * 2);
  bf16_t* wo_t = (bf16_t*)carve((size_t)2048 * 2048 * 2);
  bf16_t* qb_ = (bf16_t*)carve((size_t)64 * 2048 * 64 * 2);
  bf16_t* kb_ = (bf16_t*)carve((size_t)64 * 2048 * 64 * 2);
  bf16_t* vb_ = (bf16_t*)carve((size_t)64 * 2048 * 64 * 2);
  bf16_t* attn = (bf16_t*)carve((size_t)4096 * 2048 * 2);
  float* ct = (float*)carve((size_t)2048 * 16 * 4);
  float* st = (float*)carve((size_t)2048 * 16 * 4);
  if (off > ws_size) return;  // sentinel (known not to fire at this size)

  k_transpose_cvt<<<dim3(192, 64), dim3(32, 8), 0, stream>>>(Wqkv, wqkv_t, 2048, 6144);
  k_transpose_cvt<<<dim3(64, 64), dim3(32, 8), 0, stream>>>(Wo, wo_t, 2048, 2048);
  k_sincos<<<128, 256, 0, stream>>>(ct, st);
  // GEMM1: qkv = x @ Wqkv + bqkv, fused RoPE + head-split -> q,k,v [B*H][S][64]
  k_gemm<6144, 2048, true, 1, false><<<dim3(48, 32), 256, 0, stream>>>(
      x, wqkv_t, bqkv, qb_, kb_, vb_, ct, st);
  k_attn<<<dim3(32, 64), 256, 0, stream>>>(qb_, kb_, vb_, attn);
  // GEMM2: out(fp32) = attn @ Wo + bo
  k_gemm<2048, 2048, false, 0, true><<<dim3(16, 32), 256, 0, stream>>>(
      attn, wo_t, bo, out, nullptr, nullptr, nullptr, nullptr);
}

// Round 5
// 390.378 us; speedup vs baseline: 1.6018x; 1.6018x over previous
//
#include <hip/hip_runtime.h>
#include <hip/hip_bf16.h>
#include <math.h>

typedef __bf16 bf16_t;
typedef __bf16 bf16x8 __attribute__((ext_vector_type(8)));
typedef __bf16 bf16x2 __attribute__((ext_vector_type(2)));
typedef float f32x4 __attribute__((ext_vector_type(4)));
typedef unsigned int u32;
typedef u32 u32x4 __attribute__((ext_vector_type(4)));

#define MFMA16(a,b,c) __builtin_amdgcn_mfma_f32_16x16x32_bf16((a),(b),(c),0,0,0)

// ---------------- fp32 [R][C] -> bf16 [C][R] transpose-convert ----------------
__global__ void k_transpose_cvt(const float* __restrict__ in, bf16_t* __restrict__ out,
                                int R, int C) {
  __shared__ float tile[32][33];
  int c0 = blockIdx.x * 32, r0 = blockIdx.y * 32;
  int x = threadIdx.x, y = threadIdx.y;  // block (32,8)
#pragma unroll
  for (int i = 0; i < 32; i += 8) tile[y + i][x] = in[(size_t)(r0 + y + i) * C + c0 + x];
  __syncthreads();
#pragma unroll
  for (int i = 0; i < 32; i += 8)
    out[(size_t)(c0 + y + i) * R + r0 + x] = (bf16_t)tile[x][y + i];
}

// ---------------- bf16 [bh][2048][64] -> [bh][64][2048] transpose ----------------
__global__ void k_transpose_v(const bf16_t* __restrict__ in, bf16_t* __restrict__ out) {
  __shared__ bf16_t tile[64][65];
  const int s0 = blockIdx.x * 64, bh = blockIdx.y;
  const int x = threadIdx.x, y = threadIdx.y;  // block (64,4)
  const size_t ibase = (size_t)bh * 2048 * 64;
  const size_t obase = (size_t)bh * 64 * 2048;
#pragma unroll
  for (int i = 0; i < 64; i += 4) tile[i + y][x] = in[ibase + (size_t)(s0 + i + y) * 64 + x];
  __syncthreads();
#pragma unroll
  for (int i = 0; i < 64; i += 4)
    out[obase + (size_t)(i + y) * 2048 + s0 + x] = tile[x][i + y];
}

// ---------------- RoPE cos/sin table: [2048][16] each ----------------
__global__ void k_sincos(float* __restrict__ ct, float* __restrict__ st) {
  int idx = blockIdx.x * blockDim.x + threadIdx.x;  // 0..32767
  int pos = idx >> 4, i = idx & 15;
  float invf = powf(10000.0f, -(float)i / 16.0f);
  float ang = (float)pos * invf;
  ct[idx] = cosf(ang);
  st[idx] = sinf(ang);
}

// ---------------- bf16 MFMA GEMM (round-3 verbatim) ----------------
template <int N, int K, bool A_FP32, int EPI, bool OUT_F32>
__global__ __launch_bounds__(256) void k_gemm(const void* __restrict__ Av,
                                              const bf16_t* __restrict__ Bt,
                                              const float* __restrict__ bias,
                                              void* __restrict__ C0, bf16_t* __restrict__ C1,
                                              bf16_t* __restrict__ C2,
                                              const float* __restrict__ ct,
                                              const float* __restrict__ st) {
  __shared__ alignas(16) bf16_t As[128 * 64];
  __shared__ alignas(16) bf16_t Bs[128 * 64];
  const int tid = threadIdx.x;
  const int lane = tid & 63;
  const int lane15 = lane & 15, g = lane >> 4;
  const int wave = tid >> 6;
  const int wr = wave >> 1, wc = wave & 1;
  const int rowBase = blockIdx.y * 128, colBase = blockIdx.x * 128;
  f32x4 acc[4][4] = {};
  for (int kt = 0; kt < K; kt += 64) {
#pragma unroll
    for (int i = 0; i < 4; ++i) {
      int c = i * 256 + tid;
      int r = c >> 3, k8 = (c & 7) * 8;
      if constexpr (A_FP32) {
        const float* src = (const float*)Av + (size_t)(rowBase + r) * K + kt + k8;
        float4 a0 = *(const float4*)src;
        float4 a1 = *(const float4*)(src + 4);
        bf16x8 o;
        o[0] = (bf16_t)a0.x; o[1] = (bf16_t)a0.y; o[2] = (bf16_t)a0.z; o[3] = (bf16_t)a0.w;
        o[4] = (bf16_t)a1.x; o[5] = (bf16_t)a1.y; o[6] = (bf16_t)a1.z; o[7] = (bf16_t)a1.w;
        *(bf16x8*)&As[r * 64 + k8] = o;
      } else {
        *(bf16x8*)&As[r * 64 + k8] =
            *(const bf16x8*)((const bf16_t*)Av + (size_t)(rowBase + r) * K + kt + k8);
      }
      *(bf16x8*)&Bs[r * 64 + k8] = *(const bf16x8*)&Bt[(size_t)(colBase + r) * K + kt + k8];
    }
    __syncthreads();
#pragma unroll
    for (int kk = 0; kk < 2; ++kk) {
      bf16x8 af[4], bfr[4];
#pragma unroll
      for (int m = 0; m < 4; ++m)
        af[m] = *(const bf16x8*)&As[(wr * 64 + m * 16 + lane15) * 64 + kk * 32 + g * 8];
#pragma unroll
      for (int n = 0; n < 4; ++n)
        bfr[n] = *(const bf16x8*)&Bs[(wc * 64 + n * 16 + lane15) * 64 + kk * 32 + g * 8];
#pragma unroll
      for (int m = 0; m < 4; ++m)
#pragma unroll
        for (int n = 0; n < 4; ++n) acc[m][n] = MFMA16(af[m], bfr[n], acc[m][n]);
    }
    __syncthreads();
  }
  if constexpr (EPI == 0) {
#pragma unroll
    for (int m = 0; m < 4; ++m)
#pragma unroll
      for (int n = 0; n < 4; ++n) {
        int ccol = colBase + wc * 64 + n * 16 + lane15;
        float bb = bias[ccol];
#pragma unroll
        for (int j = 0; j < 4; ++j) {
          int crow = rowBase + wr * 64 + m * 16 + g * 4 + j;
          if constexpr (OUT_F32)
            ((float*)C0)[(size_t)crow * N + ccol] = acc[m][n][j] + bb;
          else
            ((bf16_t*)C0)[(size_t)crow * N + ccol] = (bf16_t)(acc[m][n][j] + bb);
        }
      }
  } else {
    const int colb = colBase + wc * 64;
    const int which = colb >> 11;
    const int h = (colb >> 6) & 31;
    bf16_t* dst = which == 0 ? (bf16_t*)C0 : which == 1 ? C1 : C2;
    float bb[4];
#pragma unroll
    for (int n = 0; n < 4; ++n) bb[n] = bias[colb + n * 16 + lane15];
#pragma unroll
    for (int m = 0; m < 4; ++m)
#pragma unroll
      for (int j = 0; j < 4; ++j) {
        int row = rowBase + wr * 64 + m * 16 + g * 4 + j;
        int s = row & 2047, b = row >> 11;
        float v[4];
#pragma unroll
        for (int n = 0; n < 4; ++n) v[n] = acc[m][n][j] + bb[n];
        if (which < 2) {
          float c = ct[s * 16 + lane15], sn = st[s * 16 + lane15];
          float a = v[0], b2 = v[1];
          v[0] = a * c - b2 * sn;
          v[1] = a * sn + b2 * c;
        }
        bf16_t* drow = dst + ((size_t)(b * 32 + h) * 2048 + s) * 64;
#pragma unroll
        for (int n = 0; n < 4; ++n) drow[n * 16 + lane15] = (bf16_t)v[n];
      }
  }
}

// ---------------- causal flash attention v2: swapped QK^T, swizzled LDS ----------------
// grid (16, 64): block i handles qb = 31-i then qb = i (33 tiles total, balanced).
// 256 threads = 4 waves; wave owns 16 queries. K,V^T staged in swizzled LDS.
// S^T = K @ Q^T via mfma(K,Q): lane holds k = n*16+g*4+j (j=reg), q = qg0+lane15.
__global__ __launch_bounds__(256) void k_attn(const bf16_t* __restrict__ q,
                                              const bf16_t* __restrict__ kbuf,
                                              const bf16_t* __restrict__ vT,
                                              bf16_t* __restrict__ attn_out) {
  __shared__ alignas(16) char KsB[64 * 128];
  __shared__ alignas(16) char VtB[64 * 128];
  const int tid = threadIdx.x, lane = tid & 63, wave = tid >> 6;
  const int lane15 = lane & 15, g = lane >> 4;
  const int bh = blockIdx.y, b = bh >> 5, h = bh & 31;
  const size_t base = (size_t)bh * 2048 * 64;   // q/k row-major [s][d]
  const size_t baseT = (size_t)bh * 64 * 2048;  // vT [d][s]
  const int swzL = (lane15 & 7) << 4;           // frag-read swizzle

  for (int pass = 0; pass < 2; ++pass) {
    const int qb = pass == 0 ? (31 - (int)blockIdx.x) : (int)blockIdx.x;
    const int qg0 = qb * 64 + wave * 16;
    bf16x8 aq[2];  // Q as B-operand: col=q=lane15 row, 8 contiguous d
#pragma unroll
    for (int kk = 0; kk < 2; ++kk)
      aq[kk] = *(const bf16x8*)&q[base + (size_t)(qg0 + lane15) * 64 + kk * 32 + g * 8];
    float m_r = -INFINITY, l_r = 0.f;
    f32x4 o[4] = {};

    for (int t = 0; t <= qb; ++t) {
      {  // stage K (row-major, swizzled) and V^T (row-major in d, swizzled)
        int r = tid >> 2, d0 = (tid & 3) * 16;
        bf16x8 k0 = *(const bf16x8*)&kbuf[base + (size_t)(t * 64 + r) * 64 + d0];
        bf16x8 k1 = *(const bf16x8*)&kbuf[base + (size_t)(t * 64 + r) * 64 + d0 + 8];
        int kb0 = r * 128 + d0 * 2, swzr = (r & 7) << 4;
        *(bf16x8*)(KsB + ((kb0) ^ swzr)) = k0;
        *(bf16x8*)(KsB + ((kb0 + 16) ^ swzr)) = k1;
#pragma unroll
        for (int cc = 0; cc < 2; ++cc) {
          int c = cc * 256 + tid;
          int d = c >> 3, kv8 = (c & 7) * 8;
          bf16x8 vv = *(const bf16x8*)&vT[baseT + (size_t)d * 2048 + t * 64 + kv8];
          *(bf16x8*)(VtB + ((d * 128 + kv8 * 2) ^ ((d & 7) << 4))) = vv;
        }
      }
      __syncthreads();
      // S^T block n: rows k = n*16+lane15 of K as A-operand
      f32x4 sv[4];
#pragma unroll
      for (int n = 0; n < 4; ++n) {
        f32x4 acc = {};
#pragma unroll
        for (int kk = 0; kk < 2; ++kk) {
          bf16x8 bk = *(const bf16x8*)(KsB + (((n * 16 + lane15) * 128 + (kk * 32 + g * 8) * 2) ^ swzL));
          acc = MFMA16(bk, aq[kk], acc);
        }
        sv[n] = acc;
      }
      // scale (+ causal mask only on the diagonal tile)
#pragma unroll
      for (int n = 0; n < 4; ++n)
#pragma unroll
        for (int j = 0; j < 4; ++j) sv[n][j] *= 0.125f;
      if (t == qb) {
        const int qg = qg0 + lane15;
#pragma unroll
        for (int n = 0; n < 4; ++n)
#pragma unroll
          for (int j = 0; j < 4; ++j)
            if (t * 64 + n * 16 + g * 4 + j > qg) sv[n][j] = -1e30f;
      }
      // online softmax: per-lane column (q = qg0+lane15), cross-g reduce
      float mt = sv[0][0];
#pragma unroll
      for (int n = 0; n < 4; ++n)
#pragma unroll
        for (int j = 0; j < 4; ++j) mt = fmaxf(mt, sv[n][j]);
      mt = fmaxf(mt, __shfl_xor(mt, 16));
      mt = fmaxf(mt, __shfl_xor(mt, 32));
      float mn = fmaxf(m_r, mt);
      float corr = expf(m_r - mn);
      float rs = 0.f;
      float p[4][4];
#pragma unroll
      for (int n = 0; n < 4; ++n)
#pragma unroll
        for (int j = 0; j < 4; ++j) {
          float pv = expf(sv[n][j] - mn);
          p[n][j] = pv;
          rs += pv;
        }
      rs += __shfl_xor(rs, 16);
      rs += __shfl_xor(rs, 32);
      l_r = l_r * corr + rs;
      m_r = mn;
      // pack P to bf16 pairs: pk[n][h] = (k = n*16 + own_g*4 + 2h, +1)
      u32 pk[4][2];
#pragma unroll
      for (int n = 0; n < 4; ++n) {
#pragma unroll
        for (int hh = 0; hh < 2; ++hh) {
          union { bf16x2 v; u32 u; } cv;
          cv.v[0] = (bf16_t)p[n][2 * hh];
          cv.v[1] = (bf16_t)p[n][2 * hh + 1];
          pk[n][hh] = cv.u;
        }
      }
      // rescale O by corr of each output row q_local = g*4+j
      float cb[4];
#pragma unroll
      for (int j = 0; j < 4; ++j) cb[j] = __shfl(corr, g * 4 + j);
#pragma unroll
      for (int f = 0; f < 4; ++f)
#pragma unroll
        for (int j = 0; j < 4; ++j) o[f][j] *= cb[j];
      // PV: A-operand P[q=lane15][k contig] gathered cross-lane from pk
      const int srcA = ((g & 1) << 5) + lane15;  // provider g' = 2*(g&1)
      const int srcB = srcA + 16;
      const bool hi = (g >> 1) != 0;             // n-block = 2kk + (g>>1)
#pragma unroll
      for (int kk = 0; kk < 2; ++kk) {
        u32 a0 = __shfl(pk[2 * kk][0], srcA), b0 = __shfl(pk[2 * kk + 1][0], srcA);
        u32 a1 = __shfl(pk[2 * kk][1], srcA), b1 = __shfl(pk[2 * kk + 1][1], srcA);
        u32 a2 = __shfl(pk[2 * kk][0], srcB), b2 = __shfl(pk[2 * kk + 1][0], srcB);
        u32 a3 = __shfl(pk[2 * kk][1], srcB), b3 = __shfl(pk[2 * kk + 1][1], srcB);
        union { u32x4 u; bf16x8 v; } pa;
        pa.u[0] = hi ? b0 : a0;
        pa.u[1] = hi ? b1 : a1;
        pa.u[2] = hi ? b2 : a2;
        pa.u[3] = hi ? b3 : a3;
#pragma unroll
        for (int f = 0; f < 4; ++f) {
          bf16x8 bv = *(const bf16x8*)(VtB + (((f * 16 + lane15) * 128 + (kk * 32 + g * 8) * 2) ^ swzL));
          o[f] = MFMA16(pa.v, bv, o[f]);
        }
      }
      __syncthreads();
    }
    // epilogue: O rows q = qg0 + g*4 + j, cols d = f*16 + lane15
    float lb[4];
#pragma unroll
    for (int j = 0; j < 4; ++j) lb[j] = __shfl(l_r, g * 4 + j);
#pragma unroll
    for (int f = 0; f < 4; ++f)
#pragma unroll
      for (int j = 0; j < 4; ++j) {
        int qg = qg0 + g * 4 + j;
        attn_out[(size_t)(b * 2048 + qg) * 2048 + h * 64 + f * 16 + lane15] =
            (bf16_t)(o[f][j] / lb[j]);
      }
  }
}

extern "C" void kernel_launch(void* const* d_in, const int* in_sizes, int n_in, void* d_out,
                              int out_size, void* d_ws, size_t ws_size, hipStream_t stream) {
  const float* x = (const float*)d_in[0];
  const float* Wqkv = (const float*)d_in[1];
  const float* bqkv = (const float*)d_in[2];
  const float* Wo = (const float*)d_in[3];
  const float* bo = (const float*)d_in[4];
  float* out = (float*)d_out;  // fp32 output

  char* ws = (char*)d_ws;
  size_t off = 0;
  auto carve = [&](size_t bytes) {
    void* p = ws + off;
    off += (bytes + 255) & ~(size_t)255;
    return p;
  };
  bf16_t* wqkv_t = (bf16_t*)carve((size_t)6144 * 2048 * 2);
  bf16_t* wo_t = (bf16_t*)carve((size_t)2048 * 2048 * 2);
  bf16_t* qb_ = (bf16_t*)carve((size_t)64 * 2048 * 64 * 2);
  bf16_t* kb_ = (bf16_t*)carve((size_t)64 * 2048 * 64 * 2);
  bf16_t* vb_ = (bf16_t*)carve((size_t)64 * 2048 * 64 * 2);
  bf16_t* vbT = (bf16_t*)carve((size_t)64 * 64 * 2048 * 2);
  bf16_t* attn = (bf16_t*)carve((size_t)4096 * 2048 * 2);
  float* ct = (float*)carve((size_t)2048 * 16 * 4);
  float* st = (float*)carve((size_t)2048 * 16 * 4);
  if (off > ws_size) return;  // sentinel

  k_transpose_cvt<<<dim3(192, 64), dim3(32, 8), 0, stream>>>(Wqkv, wqkv_t, 2048, 6144);
  k_transpose_cvt<<<dim3(64, 64), dim3(32, 8), 0, stream>>>(Wo, wo_t, 2048, 2048);
  k_sincos<<<128, 256, 0, stream>>>(ct, st);
  k_gemm<6144, 2048, true, 1, false><<<dim3(48, 32), 256, 0, stream>>>(
      x, wqkv_t, bqkv, qb_, kb_, vb_, ct, st);
  k_transpose_v<<<dim3(32, 64), dim3(64, 4), 0, stream>>>(vb_, vbT);
  k_attn<<<dim3(16, 64), 256, 0, stream>>>(qb_, kb_, vbT, attn);
  k_gemm<2048, 2048, false, 0, true><<<dim3(16, 32), 256, 0, stream>>>(
      attn, wo_t, bo, out, nullptr, nullptr, nullptr, nullptr);
}

// Round 6
// 362.406 us; speedup vs baseline: 1.7254x; 1.0772x over previous
//
#include <hip/hip_runtime.h>
#include <hip/hip_bf16.h>
#include <math.h>

typedef __bf16 bf16_t;
typedef __bf16 bf16x8 __attribute__((ext_vector_type(8)));
typedef __bf16 bf16x2 __attribute__((ext_vector_type(2)));
typedef float f32x4 __attribute__((ext_vector_type(4)));
typedef unsigned int u32;
typedef u32 u32x4 __attribute__((ext_vector_type(4)));

#define MFMA16(a,b,c) __builtin_amdgcn_mfma_f32_16x16x32_bf16((a),(b),(c),0,0,0)

// async global->LDS, 16B per lane; LDS dest = wave-uniform base + lane*16
__device__ __forceinline__ void gload_lds16(const bf16_t* g, bf16_t* l) {
  __builtin_amdgcn_global_load_lds(
      (const __attribute__((address_space(1))) void*)g,
      (__attribute__((address_space(3))) void*)l, 16, 0, 0);
}

// ---------------- fp32 -> bf16 flat convert (8/thread) ----------------
__global__ void k_cvt(const float* __restrict__ in, bf16_t* __restrict__ out, int n) {
  int i = (blockIdx.x * blockDim.x + threadIdx.x) * 8;
  int stride = gridDim.x * blockDim.x * 8;
  for (; i < n; i += stride) {
    float4 a = *(const float4*)&in[i];
    float4 b = *(const float4*)&in[i + 4];
    bf16x8 o;
    o[0] = (bf16_t)a.x; o[1] = (bf16_t)a.y; o[2] = (bf16_t)a.z; o[3] = (bf16_t)a.w;
    o[4] = (bf16_t)b.x; o[5] = (bf16_t)b.y; o[6] = (bf16_t)b.z; o[7] = (bf16_t)b.w;
    *(bf16x8*)&out[i] = o;
  }
}

// ---------------- fp32 [R][C] -> bf16 [C][R] transpose-convert ----------------
__global__ void k_transpose_cvt(const float* __restrict__ in, bf16_t* __restrict__ out,
                                int R, int C) {
  __shared__ float tile[32][33];
  int c0 = blockIdx.x * 32, r0 = blockIdx.y * 32;
  int x = threadIdx.x, y = threadIdx.y;  // block (32,8)
#pragma unroll
  for (int i = 0; i < 32; i += 8) tile[y + i][x] = in[(size_t)(r0 + y + i) * C + c0 + x];
  __syncthreads();
#pragma unroll
  for (int i = 0; i < 32; i += 8)
    out[(size_t)(c0 + y + i) * R + r0 + x] = (bf16_t)tile[x][y + i];
}

// ---------------- bf16 [bh][2048][64] -> [bh][64][2048] transpose ----------------
__global__ void k_transpose_v(const bf16_t* __restrict__ in, bf16_t* __restrict__ out) {
  __shared__ bf16_t tile[64][65];
  const int s0 = blockIdx.x * 64, bh = blockIdx.y;
  const int x = threadIdx.x, y = threadIdx.y;  // block (64,4)
  const size_t ibase = (size_t)bh * 2048 * 64;
  const size_t obase = (size_t)bh * 64 * 2048;
#pragma unroll
  for (int i = 0; i < 64; i += 4) tile[i + y][x] = in[ibase + (size_t)(s0 + i + y) * 64 + x];
  __syncthreads();
#pragma unroll
  for (int i = 0; i < 64; i += 4)
    out[obase + (size_t)(i + y) * 2048 + s0 + x] = tile[x][i + y];
}

// ---------------- RoPE cos/sin table: [2048][16] each ----------------
__global__ void k_sincos(float* __restrict__ ct, float* __restrict__ st) {
  int idx = blockIdx.x * blockDim.x + threadIdx.x;  // 0..32767
  int pos = idx >> 4, i = idx & 15;
  float invf = powf(10000.0f, -(float)i / 16.0f);
  float ang = (float)pos * invf;
  ct[idx] = cosf(ang);
  st[idx] = sinf(ang);
}

// ---------------- bf16 MFMA GEMM, global_load_lds staging (m97 structure) ----------------
// C[M][N] = A[M][K] @ Bt[N][K]^T + bias. 128x128 tile, BK=64, 4 waves 2x2.
// EPI=0: plain store to C0 (fp32 if OUT_F32 else bf16).
// EPI=1: RoPE + head-split epilogue writing q/k/v [B*H][S][64] (C0=q, C1=k, C2=v).
template <int N, int K, int EPI, bool OUT_F32>
__global__ __launch_bounds__(256) void k_gemm(const bf16_t* __restrict__ A,
                                              const bf16_t* __restrict__ Bt,
                                              const float* __restrict__ bias,
                                              void* __restrict__ C0, bf16_t* __restrict__ C1,
                                              bf16_t* __restrict__ C2,
                                              const float* __restrict__ ct,
                                              const float* __restrict__ st) {
  __shared__ alignas(16) bf16_t As[128 * 64];
  __shared__ alignas(16) bf16_t Bs[128 * 64];
  const int tid = threadIdx.x;
  const int lane = tid & 63;
  const int lane15 = lane & 15, g = lane >> 4;
  const int wave = tid >> 6;
  const int wr = wave >> 1, wc = wave & 1;
  const int lrow = lane >> 3;        // 0..7: row within 8-row stripe
  const int lcol = (lane & 7) * 8;   // element offset within row
  const int rowBase = blockIdx.y * 128, colBase = blockIdx.x * 128;
  f32x4 acc[4][4] = {};
  for (int kt = 0; kt < K; kt += 64) {
    // async stage: each wave issues 4 A-loads + 4 B-loads of 1 KiB (8 rows) each
#pragma unroll
    for (int i = 0; i < 4; ++i) {
      int r = wave * 32 + i * 8;  // wave-uniform stripe base
      gload_lds16(&A[(size_t)(rowBase + r + lrow) * K + kt + lcol], &As[r * 64]);
      gload_lds16(&Bt[(size_t)(colBase + r + lrow) * K + kt + lcol], &Bs[r * 64]);
    }
    __syncthreads();  // compiler drains vmcnt before barrier
#pragma unroll
    for (int kk = 0; kk < 2; ++kk) {
      bf16x8 af[4], bfr[4];
#pragma unroll
      for (int m = 0; m < 4; ++m)
        af[m] = *(const bf16x8*)&As[(wr * 64 + m * 16 + lane15) * 64 + kk * 32 + g * 8];
#pragma unroll
      for (int n = 0; n < 4; ++n)
        bfr[n] = *(const bf16x8*)&Bs[(wc * 64 + n * 16 + lane15) * 64 + kk * 32 + g * 8];
#pragma unroll
      for (int m = 0; m < 4; ++m)
#pragma unroll
        for (int n = 0; n < 4; ++n) acc[m][n] = MFMA16(af[m], bfr[n], acc[m][n]);
    }
    __syncthreads();
  }
  // C/D layout: col=lane&15, row=(lane>>4)*4+j
  if constexpr (EPI == 0) {
#pragma unroll
    for (int m = 0; m < 4; ++m)
#pragma unroll
      for (int n = 0; n < 4; ++n) {
        int ccol = colBase + wc * 64 + n * 16 + lane15;
        float bb = bias[ccol];
#pragma unroll
        for (int j = 0; j < 4; ++j) {
          int crow = rowBase + wr * 64 + m * 16 + g * 4 + j;
          if constexpr (OUT_F32)
            ((float*)C0)[(size_t)crow * N + ccol] = acc[m][n][j] + bb;
          else
            ((bf16_t*)C0)[(size_t)crow * N + ccol] = (bf16_t)(acc[m][n][j] + bb);
        }
      }
  } else {
    const int colb = colBase + wc * 64;  // 64-aligned -> one head
    const int which = colb >> 11;        // 0=q 1=k 2=v
    const int h = (colb >> 6) & 31;
    bf16_t* dst = which == 0 ? (bf16_t*)C0 : which == 1 ? C1 : C2;
    float bb[4];
#pragma unroll
    for (int n = 0; n < 4; ++n) bb[n] = bias[colb + n * 16 + lane15];
#pragma unroll
    for (int m = 0; m < 4; ++m)
#pragma unroll
      for (int j = 0; j < 4; ++j) {
        int row = rowBase + wr * 64 + m * 16 + g * 4 + j;
        int s = row & 2047, b = row >> 11;
        float v[4];
#pragma unroll
        for (int n = 0; n < 4; ++n) v[n] = acc[m][n][j] + bb[n];
        if (which < 2) {  // rope pair (d, d+16), d = lane15
          float c = ct[s * 16 + lane15], sn = st[s * 16 + lane15];
          float a = v[0], b2 = v[1];
          v[0] = a * c - b2 * sn;
          v[1] = a * sn + b2 * c;
        }
        bf16_t* drow = dst + ((size_t)(b * 32 + h) * 2048 + s) * 64;
#pragma unroll
        for (int n = 0; n < 4; ++n) drow[n * 16 + lane15] = (bf16_t)v[n];
      }
  }
}

// ---------------- causal flash attention v2 (round-5 verbatim) ----------------
__global__ __launch_bounds__(256) void k_attn(const bf16_t* __restrict__ q,
                                              const bf16_t* __restrict__ kbuf,
                                              const bf16_t* __restrict__ vT,
                                              bf16_t* __restrict__ attn_out) {
  __shared__ alignas(16) char KsB[64 * 128];
  __shared__ alignas(16) char VtB[64 * 128];
  const int tid = threadIdx.x, lane = tid & 63, wave = tid >> 6;
  const int lane15 = lane & 15, g = lane >> 4;
  const int bh = blockIdx.y, b = bh >> 5, h = bh & 31;
  const size_t base = (size_t)bh * 2048 * 64;
  const size_t baseT = (size_t)bh * 64 * 2048;
  const int swzL = (lane15 & 7) << 4;

  for (int pass = 0; pass < 2; ++pass) {
    const int qb = pass == 0 ? (31 - (int)blockIdx.x) : (int)blockIdx.x;
    const int qg0 = qb * 64 + wave * 16;
    bf16x8 aq[2];
#pragma unroll
    for (int kk = 0; kk < 2; ++kk)
      aq[kk] = *(const bf16x8*)&q[base + (size_t)(qg0 + lane15) * 64 + kk * 32 + g * 8];
    float m_r = -INFINITY, l_r = 0.f;
    f32x4 o[4] = {};

    for (int t = 0; t <= qb; ++t) {
      {
        int r = tid >> 2, d0 = (tid & 3) * 16;
        bf16x8 k0 = *(const bf16x8*)&kbuf[base + (size_t)(t * 64 + r) * 64 + d0];
        bf16x8 k1 = *(const bf16x8*)&kbuf[base + (size_t)(t * 64 + r) * 64 + d0 + 8];
        int kb0 = r * 128 + d0 * 2, swzr = (r & 7) << 4;
        *(bf16x8*)(KsB + ((kb0) ^ swzr)) = k0;
        *(bf16x8*)(KsB + ((kb0 + 16) ^ swzr)) = k1;
#pragma unroll
        for (int cc = 0; cc < 2; ++cc) {
          int c = cc * 256 + tid;
          int d = c >> 3, kv8 = (c & 7) * 8;
          bf16x8 vv = *(const bf16x8*)&vT[baseT + (size_t)d * 2048 + t * 64 + kv8];
          *(bf16x8*)(VtB + ((d * 128 + kv8 * 2) ^ ((d & 7) << 4))) = vv;
        }
      }
      __syncthreads();
      f32x4 sv[4];
#pragma unroll
      for (int n = 0; n < 4; ++n) {
        f32x4 acc = {};
#pragma unroll
        for (int kk = 0; kk < 2; ++kk) {
          bf16x8 bk = *(const bf16x8*)(KsB + (((n * 16 + lane15) * 128 + (kk * 32 + g * 8) * 2) ^ swzL));
          acc = MFMA16(bk, aq[kk], acc);
        }
        sv[n] = acc;
      }
#pragma unroll
      for (int n = 0; n < 4; ++n)
#pragma unroll
        for (int j = 0; j < 4; ++j) sv[n][j] *= 0.125f;
      if (t == qb) {
        const int qg = qg0 + lane15;
#pragma unroll
        for (int n = 0; n < 4; ++n)
#pragma unroll
          for (int j = 0; j < 4; ++j)
            if (t * 64 + n * 16 + g * 4 + j > qg) sv[n][j] = -1e30f;
      }
      float mt = sv[0][0];
#pragma unroll
      for (int n = 0; n < 4; ++n)
#pragma unroll
        for (int j = 0; j < 4; ++j) mt = fmaxf(mt, sv[n][j]);
      mt = fmaxf(mt, __shfl_xor(mt, 16));
      mt = fmaxf(mt, __shfl_xor(mt, 32));
      float mn = fmaxf(m_r, mt);
      float corr = expf(m_r - mn);
      float rs = 0.f;
      float p[4][4];
#pragma unroll
      for (int n = 0; n < 4; ++n)
#pragma unroll
        for (int j = 0; j < 4; ++j) {
          float pv = expf(sv[n][j] - mn);
          p[n][j] = pv;
          rs += pv;
        }
      rs += __shfl_xor(rs, 16);
      rs += __shfl_xor(rs, 32);
      l_r = l_r * corr + rs;
      m_r = mn;
      u32 pk[4][2];
#pragma unroll
      for (int n = 0; n < 4; ++n) {
#pragma unroll
        for (int hh = 0; hh < 2; ++hh) {
          union { bf16x2 v; u32 u; } cv;
          cv.v[0] = (bf16_t)p[n][2 * hh];
          cv.v[1] = (bf16_t)p[n][2 * hh + 1];
          pk[n][hh] = cv.u;
        }
      }
      float cb[4];
#pragma unroll
      for (int j = 0; j < 4; ++j) cb[j] = __shfl(corr, g * 4 + j);
#pragma unroll
      for (int f = 0; f < 4; ++f)
#pragma unroll
        for (int j = 0; j < 4; ++j) o[f][j] *= cb[j];
      const int srcA = ((g & 1) << 5) + lane15;
      const int srcB = srcA + 16;
      const bool hi = (g >> 1) != 0;
#pragma unroll
      for (int kk = 0; kk < 2; ++kk) {
        u32 a0 = __shfl(pk[2 * kk][0], srcA), b0 = __shfl(pk[2 * kk + 1][0], srcA);
        u32 a1 = __shfl(pk[2 * kk][1], srcA), b1 = __shfl(pk[2 * kk + 1][1], srcA);
        u32 a2 = __shfl(pk[2 * kk][0], srcB), b2 = __shfl(pk[2 * kk + 1][0], srcB);
        u32 a3 = __shfl(pk[2 * kk][1], srcB), b3 = __shfl(pk[2 * kk + 1][1], srcB);
        union { u32x4 u; bf16x8 v; } pa;
        pa.u[0] = hi ? b0 : a0;
        pa.u[1] = hi ? b1 : a1;
        pa.u[2] = hi ? b2 : a2;
        pa.u[3] = hi ? b3 : a3;
#pragma unroll
        for (int f = 0; f < 4; ++f) {
          bf16x8 bv = *(const bf16x8*)(VtB + (((f * 16 + lane15) * 128 + (kk * 32 + g * 8) * 2) ^ swzL));
          o[f] = MFMA16(pa.v, bv, o[f]);
        }
      }
      __syncthreads();
    }
    float lb[4];
#pragma unroll
    for (int j = 0; j < 4; ++j) lb[j] = __shfl(l_r, g * 4 + j);
#pragma unroll
    for (int f = 0; f < 4; ++f)
#pragma unroll
      for (int j = 0; j < 4; ++j) {
        int qg = qg0 + g * 4 + j;
        attn_out[(size_t)(b * 2048 + qg) * 2048 + h * 64 + f * 16 + lane15] =
            (bf16_t)(o[f][j] / lb[j]);
      }
  }
}

extern "C" void kernel_launch(void* const* d_in, const int* in_sizes, int n_in, void* d_out,
                              int out_size, void* d_ws, size_t ws_size, hipStream_t stream) {
  const float* x = (const float*)d_in[0];
  const float* Wqkv = (const float*)d_in[1];
  const float* bqkv = (const float*)d_in[2];
  const float* Wo = (const float*)d_in[3];
  const float* bo = (const float*)d_in[4];
  float* out = (float*)d_out;  // fp32 output

  char* ws = (char*)d_ws;
  size_t off = 0;
  auto carve = [&](size_t bytes) {
    void* p = ws + off;
    off += (bytes + 255) & ~(size_t)255;
    return p;
  };
  bf16_t* x_bf = (bf16_t*)carve((size_t)4096 * 2048 * 2);
  bf16_t* wqkv_t = (bf16_t*)carve((size_t)6144 * 2048 * 2);
  bf16_t* wo_t = (bf16_t*)carve((size_t)2048 * 2048 * 2);
  bf16_t* qb_ = (bf16_t*)carve((size_t)64 * 2048 * 64 * 2);
  bf16_t* kb_ = (bf16_t*)carve((size_t)64 * 2048 * 64 * 2);
  bf16_t* vb_ = (bf16_t*)carve((size_t)64 * 2048 * 64 * 2);
  bf16_t* vbT = (bf16_t*)carve((size_t)64 * 64 * 2048 * 2);
  bf16_t* attn = (bf16_t*)carve((size_t)4096 * 2048 * 2);
  float* ct = (float*)carve((size_t)2048 * 16 * 4);
  float* st = (float*)carve((size_t)2048 * 16 * 4);
  if (off > ws_size) return;  // sentinel

  k_cvt<<<2048, 256, 0, stream>>>(x, x_bf, 4096 * 2048);
  k_transpose_cvt<<<dim3(192, 64), dim3(32, 8), 0, stream>>>(Wqkv, wqkv_t, 2048, 6144);
  k_transpose_cvt<<<dim3(64, 64), dim3(32, 8), 0, stream>>>(Wo, wo_t, 2048, 2048);
  k_sincos<<<128, 256, 0, stream>>>(ct, st);
  k_gemm<6144, 2048, 1, false><<<dim3(48, 32), 256, 0, stream>>>(
      x_bf, wqkv_t, bqkv, qb_, kb_, vb_, ct, st);
  k_transpose_v<<<dim3(32, 64), dim3(64, 4), 0, stream>>>(vb_, vbT);
  k_attn<<<dim3(16, 64), 256, 0, stream>>>(qb_, kb_, vbT, attn);
  k_gemm<2048, 2048, 0, true><<<dim3(16, 32), 256, 0, stream>>>(
      attn, wo_t, bo, out, nullptr, nullptr, nullptr, nullptr);
}